// Round 6
// baseline (438.465 us; speedup 1.0000x reference)
//
#include <hip/hip_runtime.h>
#include <hip/hip_bf16.h>

typedef __attribute__((ext_vector_type(4))) float f32x4;
typedef __attribute__((ext_vector_type(4))) float fl4;
typedef __attribute__((ext_vector_type(8))) short s16x8;
typedef __attribute__((ext_vector_type(4))) short s16x4;

#define SCALING_C 0.1889822365046136f
// 50*tanh(y/50) = y*(1 + y2*(P1 + y2*P2)), y2=y*y
#define POLY_P1 (-1.3333333333e-4f)   // -1/7500
#define POLY_P2 (2.1333333333e-8f)    //  2/93750000

__device__ __forceinline__ short f2bf(float f) {
  union { float f; unsigned u; } v; v.f = f;
  unsigned r = v.u + 0x7fffu + ((v.u >> 16) & 1u);
  return (short)(r >> 16);
}
__device__ __forceinline__ float bf2f(short s) {
  union { unsigned u; float f; } v; v.u = ((unsigned)(unsigned short)s) << 16;
  return v.f;
}

#define GLOAD_LDS16(g, l)                                                          \
  __builtin_amdgcn_global_load_lds(                                                \
      (const __attribute__((address_space(1))) void*)(g),                          \
      (__attribute__((address_space(3))) void*)(l), 16, 0, 0)

// ---------------- transpose + fp32->bf16 convert: WT[n][k] = bf16(W[k][n]) -----
__global__ __launch_bounds__(256)
void convT_kernel(const float* __restrict__ W, short* __restrict__ WT, int K, int N) {
  __shared__ float T[64][65];
  const int tx = threadIdx.x, ty = threadIdx.y;   // (64,4)
  const int k0 = blockIdx.x * 64, n0 = blockIdx.y * 64;
#pragma unroll
  for (int i = 0; i < 16; ++i) {
    int r = ty + i * 4;
    T[r][tx] = W[(size_t)(k0 + r) * N + n0 + tx];
  }
  __syncthreads();
#pragma unroll
  for (int i = 0; i < 16; ++i) {
    int r = ty + i * 4;
    WT[(size_t)(n0 + r) * K + k0 + tx] = f2bf(T[tx][r]);
  }
}

// ---------------- fp32 -> bf16 elementwise (hidden states) ----------------
__global__ __launch_bounds__(256)
void conv16_kernel(const float* __restrict__ X, short* __restrict__ Y, int n4) {
  int i = blockIdx.x * 256 + threadIdx.x;
  if (i < n4) {
    fl4 v = *(const fl4*)&X[(size_t)i * 4];
    s16x4 o;
    o[0] = f2bf(v[0]); o[1] = f2bf(v[1]); o[2] = f2bf(v[2]); o[3] = f2bf(v[3]);
    *(s16x4*)&Y[(size_t)i * 4] = o;
  }
}

// ---------------- GEMM: C = A @ Bt^T ; A MxK bf16 rows, Bt NxK bf16 rows -------
template<int OUT_BF16>
__global__ __launch_bounds__(256)
void gemm_bb(const short* __restrict__ A, const short* __restrict__ Bt,
             void* __restrict__ Cv, int N, int K) {
  __shared__ short As[8192];   // 128 rows x 64 shorts
  __shared__ short Bs[8192];
  const int tid = threadIdx.x;
  const int bm = blockIdx.y, bn = blockIdx.x;
  const int wid = tid >> 6, lane = tid & 63;
  const int wr = (wid >> 1) * 64, wc = (wid & 1) * 64;
  const int ar = lane & 15, g = lane >> 4;

  const f32x4 fz = {0.f, 0.f, 0.f, 0.f};
  f32x4 acc[4][4];
#pragma unroll
  for (int m = 0; m < 4; ++m)
#pragma unroll
    for (int n = 0; n < 4; ++n) acc[m][n] = fz;

  const short* Abase = A + (size_t)(bm * 128) * K;
  const short* Bbase = Bt + (size_t)(bn * 128) * K;
  const int u0 = wid * 256 + lane;

  for (int k0 = 0; k0 < K; k0 += 64) {
#pragma unroll
    for (int i = 0; i < 4; ++i) {
      int u = u0 + i * 64;
      int r = u >> 3;
      int cs = (u & 7) ^ (r & 7);
      size_t goff = (size_t)r * K + k0 + cs * 8;
      GLOAD_LDS16(Abase + goff, &As[(wid * 256 + i * 64) * 8]);
      GLOAD_LDS16(Bbase + goff, &Bs[(wid * 256 + i * 64) * 8]);
    }
    __syncthreads();
#pragma unroll
    for (int ks = 0; ks < 2; ++ks) {
      s16x8 af[4], bfr[4];
#pragma unroll
      for (int m = 0; m < 4; ++m) {
        int r = wr + m * 16 + ar;
        af[m] = *(const s16x8*)&As[r * 64 + (((ks * 4 + g) ^ (r & 7)) * 8)];
      }
#pragma unroll
      for (int n = 0; n < 4; ++n) {
        int r = wc + n * 16 + ar;
        bfr[n] = *(const s16x8*)&Bs[r * 64 + (((ks * 4 + g) ^ (r & 7)) * 8)];
      }
#pragma unroll
      for (int m = 0; m < 4; ++m)
#pragma unroll
        for (int n = 0; n < 4; ++n)
          acc[m][n] = __builtin_amdgcn_mfma_f32_16x16x32_bf16(af[m], bfr[n], acc[m][n], 0, 0, 0);
    }
    __syncthreads();
  }
  const int rr = (lane >> 4) * 4;
#pragma unroll
  for (int m = 0; m < 4; ++m)
#pragma unroll
    for (int n = 0; n < 4; ++n)
#pragma unroll
      for (int j = 0; j < 4; ++j) {
        int row = bm * 128 + wr + m * 16 + rr + j;
        int col = bn * 128 + wc + n * 16 + ar;
        if (OUT_BF16)
          ((short*)Cv)[(size_t)row * N + col] = f2bf(acc[m][n][j]);
        else
          ((float*)Cv)[(size_t)row * N + col] = acc[m][n][j];
      }
}

// ---------------- fused RMSNorm + RoPE, in-place on bf16, one wave per row -----
__global__ __launch_bounds__(256)
void normrope_kernel(short* __restrict__ X, const float* __restrict__ cosb,
                     const float* __restrict__ sinb, const float* __restrict__ w,
                     int headsPerS, int rowsPerS) {
  const int wid = threadIdx.x >> 6, lane = threadIdx.x & 63;
  const int r = blockIdx.x * 4 + wid;
  const int s = r / headsPerS, h = r % headsPerS;
  const size_t base = (size_t)(s * rowsPerS + h) * 128;
  float x1 = bf2f(X[base + lane]);
  float x2 = bf2f(X[base + 64 + lane]);
  float ss = x1 * x1 + x2 * x2;
#pragma unroll
  for (int m = 1; m < 64; m <<= 1) ss += __shfl_xor(ss, m);
  float inv = rsqrtf(ss * (1.0f / 128.0f) + 1e-6f);
  float n1 = x1 * inv * (1.0f + w[lane]);
  float n2 = x2 * inv * (1.0f + w[lane + 64]);
  float c1 = cosb[s * 128 + lane], sn1 = sinb[s * 128 + lane];
  float c2 = cosb[s * 128 + 64 + lane], sn2 = sinb[s * 128 + 64 + lane];
  X[base + lane] = f2bf(n1 * c1 - n2 * sn1);
  X[base + 64 + lane] = f2bf(n2 * c2 + n1 * sn2);
}

// ---------------- flash attention v3: reg-staged single-buffer, 3 blocks/CU ----
// Block (bx,h): q-chunk qb=31-bx (LPT), tiles kb=0..qb. 4 waves, wave owns 16 q.
// K and V staged global->regs at tile top (latency hides under compute), written
// to single-buffered LDS after the post-compute barrier (T14). LDS 41.2KB ->
// 3 blocks/CU. Polynomial softcap: 50*tanh(y/50)=y*(1+y2*(P1+y2*P2)), 1 exp.
__global__ __launch_bounds__(256, 3)
void attn_kernel(const short* __restrict__ Q, const short* __restrict__ K,
                 const short* __restrict__ V, short* __restrict__ O) {
  __shared__ short Ks[8192];      // [kv 64][d 128], chunk-XOR swizzled
  __shared__ short Vt[8192];      // [d 128][kv 64], chunk-XOR swizzled
  __shared__ short Ps[4][16][72];
  const int tid = threadIdx.x;
  const int h = blockIdx.y, hk = h >> 2;
  const int wid = tid >> 6, lane = tid & 63;
  const int ar = lane & 15, g = lane >> 4, ko = g * 8;
  const int rbase = g * 4;
  const int qb = 31 - blockIdx.x;          // LPT
  const int q0 = qb * 64 + wid * 16;

  const short* Kb = K + hk * 128;
  const short* Vb = V + hk * 128;
  const int vkv = (tid & 31) * 2;   // kv pair base
  const int vdb = tid >> 5;         // d block (16 d's)

  const f32x4 fz = {0.f, 0.f, 0.f, 0.f};
  s16x8 qf[4], kld[4], vld[4];
  f32x4 oacc[8];
  float l_l[4] = {0.f, 0.f, 0.f, 0.f};

#pragma unroll
  for (int ks = 0; ks < 4; ++ks)
    qf[ks] = *(const s16x8*)&Q[(size_t)(q0 + ar) * 4096 + h * 128 + ks * 32 + ko];
#pragma unroll
  for (int n = 0; n < 8; ++n) oacc[n] = fz;

  auto loadK = [&](int kb) {
    const short* src = Kb + (size_t)kb * 64 * 1024;
#pragma unroll
    for (int i = 0; i < 4; ++i) {
      int u = tid + i * 256;
      int r = u >> 4, c = u & 15;
      kld[i] = *(const s16x8*)(src + r * 1024 + c * 8);
    }
  };
  auto writeK = [&]() {
#pragma unroll
    for (int i = 0; i < 4; ++i) {
      int u = tid + i * 256;
      int r = u >> 4, c = u & 15;
      *(s16x8*)&Ks[(r * 16 + (c ^ (r & 7))) * 8] = kld[i];
    }
  };
  auto loadV = [&](int kb) {
    const short* src = Vb + (size_t)(kb * 64 + vkv) * 1024 + vdb * 16;
    vld[0] = *(const s16x8*)(src);
    vld[1] = *(const s16x8*)(src + 8);
    vld[2] = *(const s16x8*)(src + 1024);
    vld[3] = *(const s16x8*)(src + 1032);
  };
  auto writeVt = [&]() {
#pragma unroll
    for (int half = 0; half < 2; ++half)
#pragma unroll
      for (int j = 0; j < 8; ++j) {
        int d = vdb * 16 + half * 8 + j;     // d&7 == j
        int addr = d * 64 + (((vkv >> 3) ^ j) * 8) + (vkv & 7);
        unsigned lo = (unsigned short)vld[half][j];
        unsigned hi = (unsigned short)vld[2 + half][j];
        *(unsigned*)&Vt[addr] = lo | (hi << 16);
      }
  };

  // prologue: stage tile 0
  loadK(0); loadV(0);
  writeK(); writeVt();
  __syncthreads();

  for (int kb = 0; kb <= qb; ++kb) {
    if (kb < qb) { loadK(kb + 1); loadV(kb + 1); }   // issue early, use late

    // ---- QK^T ----
    f32x4 sacc[4];
#pragma unroll
    for (int n = 0; n < 4; ++n) sacc[n] = fz;
#pragma unroll
    for (int ks = 0; ks < 4; ++ks)
#pragma unroll
      for (int n = 0; n < 4; ++n) {
        int r = n * 16 + ar;
        s16x8 bfr = *(const s16x8*)&Ks[r * 128 + (((ks * 4 + g) ^ (r & 7)) * 8)];
        sacc[n] = __builtin_amdgcn_mfma_f32_16x16x32_bf16(qf[ks], bfr, sacc[n], 0, 0, 0);
      }

    // ---- softcap (poly) + exp, fixed max; mask only on diagonal tile ----
    const bool last = (kb == qb);
#pragma unroll
    for (int n = 0; n < 4; ++n)
#pragma unroll
      for (int j = 0; j < 4; ++j) {
        float y = sacc[n][j] * SCALING_C;
        float y2 = y * y;
        float sc = y * fmaf(y2, fmaf(y2, POLY_P2, POLY_P1), 1.0f);
        float p = __expf(sc);
        if (last) {
          int kkg = kb * 64 + n * 16 + ar;
          if (kkg > q0 + rbase + j) p = 0.f;
        }
        l_l[j] += p;
        Ps[wid][rbase + j][n * 16 + ar] = f2bf(p);
      }

    // ---- O += P V ----
#pragma unroll
    for (int ks = 0; ks < 2; ++ks) {
      s16x8 pa = *(const s16x8*)&Ps[wid][ar][ks * 32 + ko];
#pragma unroll
      for (int n = 0; n < 8; ++n) {
        int d = n * 16 + ar;
        s16x8 bfr = *(const s16x8*)&Vt[d * 64 + (((ks * 4 + g) ^ (d & 7)) * 8)];
        oacc[n] = __builtin_amdgcn_mfma_f32_16x16x32_bf16(pa, bfr, oacc[n], 0, 0, 0);
      }
    }

    if (kb < qb) {
      __syncthreads();           // all waves done reading Ks/Vt
      writeK(); writeVt();       // vmcnt waits inserted by compiler on reg use
      __syncthreads();           // staging visible
    }
  }

  // epilogue
  float rl[4];
#pragma unroll
  for (int j = 0; j < 4; ++j) {
#pragma unroll
    for (int mm = 1; mm < 16; mm <<= 1) l_l[j] += __shfl_xor(l_l[j], mm);
    rl[j] = 1.0f / l_l[j];
  }
#pragma unroll
  for (int n = 0; n < 8; ++n)
#pragma unroll
    for (int j = 0; j < 4; ++j)
      O[(size_t)(q0 + rbase + j) * 4096 + h * 128 + n * 16 + ar] =
          f2bf(oacc[n][j] * rl[j]);
}

extern "C" void kernel_launch(void* const* d_in, const int* in_sizes, int n_in,
                              void* d_out, int out_size, void* d_ws, size_t ws_size,
                              hipStream_t stream) {
  const float* hs   = (const float*)d_in[0];
  const float* cosb = (const float*)d_in[1];
  const float* sinb = (const float*)d_in[2];
  // d_in[3]: causal mask, applied analytically
  const float* Wq = (const float*)d_in[4];
  const float* Wk = (const float*)d_in[5];
  const float* Wv = (const float*)d_in[6];
  const float* Wo = (const float*)d_in[7];
  const float* qw = (const float*)d_in[8];
  const float* kw = (const float*)d_in[9];
  float* out = (float*)d_out;

  char* ws = (char*)d_ws;
  short* hsb = (short*)ws;                    // [0, 10.49M)
  short* WkT = (short*)(ws + 10485760);       // [10.49, 15.73M)
  short* WvT = (short*)(ws + 15728640);       // [15.73, 20.97M)
  short* WqT = (short*)(ws + 20971520);       // [20.97, 41.94M)
  short* Qb  = (short*)(ws + 41943040);       // [41.94, 58.72M)
  short* Kbf = (short*)(ws + 58720256);       // [58.72, 62.91M)
  short* Vbf = (short*)(ws + 62914560);       // [62.91, 67.11M)
  short* ao  = (short*)ws;                    // alias hsb+WkT+WvT (dead)
  short* WoT = (short*)(ws + 20971520);       // alias WqT (dead after Q-GEMM)

  dim3 blk(256), cblk(64, 4);
  convT_kernel<<<dim3(40, 16), cblk, 0, stream>>>(Wk, WkT, 2560, 1024);
  convT_kernel<<<dim3(40, 16), cblk, 0, stream>>>(Wv, WvT, 2560, 1024);
  convT_kernel<<<dim3(40, 64), cblk, 0, stream>>>(Wq, WqT, 2560, 4096);
  conv16_kernel<<<5120, blk, 0, stream>>>(hs, hsb, 1310720);
  gemm_bb<1><<<dim3(32, 16), blk, 0, stream>>>(hsb, WqT, Qb, 4096, 2560);
  gemm_bb<1><<<dim3(8, 16),  blk, 0, stream>>>(hsb, WkT, Kbf, 1024, 2560);
  gemm_bb<1><<<dim3(8, 16),  blk, 0, stream>>>(hsb, WvT, Vbf, 1024, 2560);
  normrope_kernel<<<16384, blk, 0, stream>>>(Qb, cosb, sinb, qw, 32, 32);
  normrope_kernel<<<4096,  blk, 0, stream>>>(Kbf, cosb, sinb, kw, 8, 8);
  convT_kernel<<<dim3(64, 40), cblk, 0, stream>>>(Wo, WoT, 4096, 2560);
  attn_kernel<<<dim3(32, 32), blk, 0, stream>>>(Qb, Kbf, Vbf, ao);
  gemm_bb<0><<<dim3(20, 16), blk, 0, stream>>>(ao, WoT, out, 2560, 4096);
}

// Round 7
// 292.601 us; speedup vs baseline: 1.4985x; 1.4985x over previous
//
#include <hip/hip_runtime.h>
#include <hip/hip_bf16.h>

typedef __attribute__((ext_vector_type(4))) float f32x4;
typedef __attribute__((ext_vector_type(4))) float fl4;
typedef __attribute__((ext_vector_type(8))) short s16x8;
typedef __attribute__((ext_vector_type(4))) short s16x4;

#define SCALING_C 0.1889822365046136f
// 50*tanh(y/50) = y*(1 + y2*(P1 + y2*P2))
#define POLY_P1 (-1.3333333333e-4f)
#define POLY_P2 (2.1333333333e-8f)
// fused QKV output row stride (shorts): 4096 Q | 1024 K | 1024 V
#define QKV_STRIDE 6144

__device__ __forceinline__ short f2bf(float f) {
  union { float f; unsigned u; } v; v.f = f;
  unsigned r = v.u + 0x7fffu + ((v.u >> 16) & 1u);
  return (short)(r >> 16);
}
__device__ __forceinline__ float bf2f(short s) {
  union { unsigned u; float f; } v; v.u = ((unsigned)(unsigned short)s) << 16;
  return v.f;
}

#define GLOAD_LDS16(g, l)                                                          \
  __builtin_amdgcn_global_load_lds(                                                \
      (const __attribute__((address_space(1))) void*)(g),                          \
      (__attribute__((address_space(3))) void*)(l), 16, 0, 0)

// ---------------- transpose + fp32->bf16 convert: WT[n][k] = bf16(W[k][n]) -----
__global__ __launch_bounds__(256)
void convT_kernel(const float* __restrict__ W, short* __restrict__ WT, int K, int N) {
  __shared__ float T[64][65];
  const int tx = threadIdx.x, ty = threadIdx.y;   // (64,4)
  const int k0 = blockIdx.x * 64, n0 = blockIdx.y * 64;
#pragma unroll
  for (int i = 0; i < 16; ++i) {
    int r = ty + i * 4;
    T[r][tx] = W[(size_t)(k0 + r) * N + n0 + tx];
  }
  __syncthreads();
#pragma unroll
  for (int i = 0; i < 16; ++i) {
    int r = ty + i * 4;
    WT[(size_t)(n0 + r) * K + k0 + tx] = f2bf(T[tx][r]);
  }
}

// ---------------- fp32 -> bf16 elementwise (hidden states) ----------------
__global__ __launch_bounds__(256)
void conv16_kernel(const float* __restrict__ X, short* __restrict__ Y, int n4) {
  int i = blockIdx.x * 256 + threadIdx.x;
  if (i < n4) {
    fl4 v = *(const fl4*)&X[(size_t)i * 4];
    s16x4 o;
    o[0] = f2bf(v[0]); o[1] = f2bf(v[1]); o[2] = f2bf(v[2]); o[3] = f2bf(v[3]);
    *(s16x4*)&Y[(size_t)i * 4] = o;
  }
}

// ---------------- GEMM: C = A @ Bt^T ; A MxK bf16 rows, Bt NxK bf16 rows -------
template<int OUT_BF16>
__global__ __launch_bounds__(256)
void gemm_bb(const short* __restrict__ A, const short* __restrict__ Bt,
             void* __restrict__ Cv, int N, int K) {
  __shared__ short As[8192];   // 128 rows x 64 shorts
  __shared__ short Bs[8192];
  const int tid = threadIdx.x;
  const int bm = blockIdx.y, bn = blockIdx.x;
  const int wid = tid >> 6, lane = tid & 63;
  const int wr = (wid >> 1) * 64, wc = (wid & 1) * 64;
  const int ar = lane & 15, g = lane >> 4;

  const f32x4 fz = {0.f, 0.f, 0.f, 0.f};
  f32x4 acc[4][4];
#pragma unroll
  for (int m = 0; m < 4; ++m)
#pragma unroll
    for (int n = 0; n < 4; ++n) acc[m][n] = fz;

  const short* Abase = A + (size_t)(bm * 128) * K;
  const short* Bbase = Bt + (size_t)(bn * 128) * K;
  const int u0 = wid * 256 + lane;

  for (int k0 = 0; k0 < K; k0 += 64) {
#pragma unroll
    for (int i = 0; i < 4; ++i) {
      int u = u0 + i * 64;
      int r = u >> 3;
      int cs = (u & 7) ^ (r & 7);
      size_t goff = (size_t)r * K + k0 + cs * 8;
      GLOAD_LDS16(Abase + goff, &As[(wid * 256 + i * 64) * 8]);
      GLOAD_LDS16(Bbase + goff, &Bs[(wid * 256 + i * 64) * 8]);
    }
    __syncthreads();
#pragma unroll
    for (int ks = 0; ks < 2; ++ks) {
      s16x8 af[4], bfr[4];
#pragma unroll
      for (int m = 0; m < 4; ++m) {
        int r = wr + m * 16 + ar;
        af[m] = *(const s16x8*)&As[r * 64 + (((ks * 4 + g) ^ (r & 7)) * 8)];
      }
#pragma unroll
      for (int n = 0; n < 4; ++n) {
        int r = wc + n * 16 + ar;
        bfr[n] = *(const s16x8*)&Bs[r * 64 + (((ks * 4 + g) ^ (r & 7)) * 8)];
      }
#pragma unroll
      for (int m = 0; m < 4; ++m)
#pragma unroll
        for (int n = 0; n < 4; ++n)
          acc[m][n] = __builtin_amdgcn_mfma_f32_16x16x32_bf16(af[m], bfr[n], acc[m][n], 0, 0, 0);
    }
    __syncthreads();
  }
  const int rr = (lane >> 4) * 4;
#pragma unroll
  for (int m = 0; m < 4; ++m)
#pragma unroll
    for (int n = 0; n < 4; ++n)
#pragma unroll
      for (int j = 0; j < 4; ++j) {
        int row = bm * 128 + wr + m * 16 + rr + j;
        int col = bn * 128 + wc + n * 16 + ar;
        if (OUT_BF16)
          ((short*)Cv)[(size_t)row * N + col] = f2bf(acc[m][n][j]);
        else
          ((float*)Cv)[(size_t)row * N + col] = acc[m][n][j];
      }
}

// ------- fused RMSNorm + RoPE on a column-slice of the fused QKV matrix --------
// row r -> (s = r>>hbits, h = r&mask); data at X[s*QKV_STRIDE + off + h*128]
__global__ __launch_bounds__(256)
void normrope_kernel(short* __restrict__ X, const float* __restrict__ cosb,
                     const float* __restrict__ sinb, const float* __restrict__ w,
                     int hbits, int off) {
  const int wid = threadIdx.x >> 6, lane = threadIdx.x & 63;
  const int r = blockIdx.x * 4 + wid;
  const int s = r >> hbits, h = r & ((1 << hbits) - 1);
  const size_t base = (size_t)s * QKV_STRIDE + off + h * 128;
  float x1 = bf2f(X[base + lane]);
  float x2 = bf2f(X[base + 64 + lane]);
  float ss = x1 * x1 + x2 * x2;
#pragma unroll
  for (int m = 1; m < 64; m <<= 1) ss += __shfl_xor(ss, m);
  float inv = rsqrtf(ss * (1.0f / 128.0f) + 1e-6f);
  float n1 = x1 * inv * (1.0f + w[lane]);
  float n2 = x2 * inv * (1.0f + w[lane + 64]);
  float c1 = cosb[s * 128 + lane], sn1 = sinb[s * 128 + lane];
  float c2 = cosb[s * 128 + 64 + lane], sn2 = sinb[s * 128 + 64 + lane];
  X[base + lane] = f2bf(n1 * c1 - n2 * sn1);
  X[base + 64 + lane] = f2bf(n2 * c2 + n1 * sn2);
}

// ---------------- flash attention v4: 8 waves, 128-q chunks, paired ------------
// Block (cA, h): chunk cA (tiles 0..2cA+1) then chunk 15-cA (tiles 0..31-2cA):
// exactly 34 tiles. Grid (8,32)=256 blocks = 2/CU resident, 16 waves/CU.
// K double-buffered via global_load_lds (0 VGPR); V reg-staged (8 VGPR) into
// single Vt with vmcnt(0)+write between two barriers. Poly softcap, fixed-max.
__global__ __launch_bounds__(512, 4)
void attn_kernel(const short* __restrict__ C, short* __restrict__ O) {
  __shared__ short Ks[2][8192];   // [kv 64][d 128], chunk-XOR swizzled
  __shared__ short Vt[8192];      // [d 128][kv 64], chunk-XOR swizzled
  __shared__ short Ps[8][16][72];
  const int tid = threadIdx.x;
  const int h = blockIdx.y, hk = h >> 2;
  const int wid = tid >> 6, lane = tid & 63;
  const int ar = lane & 15, g = lane >> 4, ko = g * 8;
  const int rbase = g * 4;
  const int cA = blockIdx.x;
  const int tA = 2 * cA + 1;           // last step of chunk A

  const short* Kb = C + 4096 + hk * 128;
  const short* Vb = C + 5120 + hk * 128;
  const int vkv = (tid & 31) * 2;      // kv pair base
  const int vdb = tid >> 5;            // d block of 8 (0..15)

  const f32x4 fz = {0.f, 0.f, 0.f, 0.f};
  s16x8 qf[4], vld[2];
  f32x4 oacc[8];
  float l_l[4] = {0.f, 0.f, 0.f, 0.f};

  int q0 = cA * 128 + wid * 16;
#pragma unroll
  for (int ks = 0; ks < 4; ++ks)
    qf[ks] = *(const s16x8*)&C[(size_t)(q0 + ar) * QKV_STRIDE + h * 128 + ks * 32 + ko];
#pragma unroll
  for (int n = 0; n < 8; ++n) oacc[n] = fz;

  auto issueK = [&](int b, int kb) {
#pragma unroll
    for (int i = 0; i < 2; ++i) {
      int u = tid + i * 512;
      int r = u >> 4, c = u & 15;
      int cs = c ^ (r & 7);
      GLOAD_LDS16(Kb + (size_t)(kb * 64 + r) * QKV_STRIDE + cs * 8, &Ks[b][u * 8]);
    }
  };
  auto loadV = [&](int kb) {
    const short* src = Vb + (size_t)(kb * 64 + vkv) * QKV_STRIDE + vdb * 8;
    vld[0] = *(const s16x8*)(src);
    vld[1] = *(const s16x8*)(src + QKV_STRIDE);
  };
  auto writeVt = [&]() {
#pragma unroll
    for (int j = 0; j < 8; ++j) {
      int d = vdb * 8 + j;                 // d&7 == j
      int addr = d * 64 + (((vkv >> 3) ^ j) * 8) + (vkv & 7);
      unsigned lo = (unsigned short)vld[0][j];
      unsigned hi = (unsigned short)vld[1][j];
      *(unsigned*)&Vt[addr] = lo | (hi << 16);
    }
  };

  // prologue: stage tile 0
  issueK(0, 0);
  loadV(0);
  asm volatile("s_waitcnt vmcnt(0)" ::: "memory");
  writeVt();
  __syncthreads();

  int buf = 0;
  for (int step = 0; step < 34; ++step) {
    const int kb = (step <= tA) ? step : step - tA - 1;
    if (step < 33) {
      const int nkb = (step + 1 <= tA) ? step + 1 : step - tA;
      issueK(buf ^ 1, nkb);
      loadV(nkb);
    }

    // ---- QK^T ----
    f32x4 sacc[4];
#pragma unroll
    for (int n = 0; n < 4; ++n) sacc[n] = fz;
#pragma unroll
    for (int ks = 0; ks < 4; ++ks)
#pragma unroll
      for (int n = 0; n < 4; ++n) {
        int r = n * 16 + ar;
        s16x8 bfr = *(const s16x8*)&Ks[buf][r * 128 + (((ks * 4 + g) ^ (r & 7)) * 8)];
        sacc[n] = __builtin_amdgcn_mfma_f32_16x16x32_bf16(qf[ks], bfr, sacc[n], 0, 0, 0);
      }

    // ---- poly softcap + exp (fixed max); mask only where diagonal reachable ----
    const bool anymask = (kb * 64 + 63 > q0);
#pragma unroll
    for (int n = 0; n < 4; ++n)
#pragma unroll
      for (int j = 0; j < 4; ++j) {
        float y = sacc[n][j] * SCALING_C;
        float y2 = y * y;
        float sc = y * fmaf(y2, fmaf(y2, POLY_P2, POLY_P1), 1.0f);
        float p = __expf(sc);
        if (anymask) {
          int kkg = kb * 64 + n * 16 + ar;
          if (kkg > q0 + rbase + j) p = 0.f;
        }
        l_l[j] += p;
        Ps[wid][rbase + j][n * 16 + ar] = f2bf(p);
      }

    // ---- O += P V ----
#pragma unroll
    for (int ks = 0; ks < 2; ++ks) {
      s16x8 pa = *(const s16x8*)&Ps[wid][ar][ks * 32 + ko];
#pragma unroll
      for (int n = 0; n < 8; ++n) {
        int d = n * 16 + ar;
        s16x8 bfr = *(const s16x8*)&Vt[d * 64 + (((ks * 4 + g) ^ (d & 7)) * 8)];
        oacc[n] = __builtin_amdgcn_mfma_f32_16x16x32_bf16(pa, bfr, oacc[n], 0, 0, 0);
      }
    }

    __syncthreads();                 // all waves done reading Vt / Ks[buf]
    if (step < 33) {
      asm volatile("s_waitcnt vmcnt(0)" ::: "memory");   // K-lds + V-reg loads done
      writeVt();
    }
    __syncthreads();                 // Vt (and Ks[buf^1]) published
    buf ^= 1;

    if (step == tA) {
      // epilogue chunk A
      float rl[4];
#pragma unroll
      for (int j = 0; j < 4; ++j) {
#pragma unroll
        for (int mm = 1; mm < 16; mm <<= 1) l_l[j] += __shfl_xor(l_l[j], mm);
        rl[j] = 1.0f / l_l[j];
      }
#pragma unroll
      for (int n = 0; n < 8; ++n)
#pragma unroll
        for (int j = 0; j < 4; ++j)
          O[(size_t)(q0 + rbase + j) * 4096 + h * 128 + n * 16 + ar] =
              f2bf(oacc[n][j] * rl[j]);
      // switch to chunk B = 15 - cA
      q0 = (15 - cA) * 128 + wid * 16;
#pragma unroll
      for (int ks = 0; ks < 4; ++ks)
        qf[ks] = *(const s16x8*)&C[(size_t)(q0 + ar) * QKV_STRIDE + h * 128 + ks * 32 + ko];
#pragma unroll
      for (int n = 0; n < 8; ++n) oacc[n] = fz;
#pragma unroll
      for (int j = 0; j < 4; ++j) l_l[j] = 0.f;
    }
  }

  // epilogue chunk B
  float rl[4];
#pragma unroll
  for (int j = 0; j < 4; ++j) {
#pragma unroll
    for (int mm = 1; mm < 16; mm <<= 1) l_l[j] += __shfl_xor(l_l[j], mm);
    rl[j] = 1.0f / l_l[j];
  }
#pragma unroll
  for (int n = 0; n < 8; ++n)
#pragma unroll
    for (int j = 0; j < 4; ++j)
      O[(size_t)(q0 + rbase + j) * 4096 + h * 128 + n * 16 + ar] =
          f2bf(oacc[n][j] * rl[j]);
}

extern "C" void kernel_launch(void* const* d_in, const int* in_sizes, int n_in,
                              void* d_out, int out_size, void* d_ws, size_t ws_size,
                              hipStream_t stream) {
  const float* hs   = (const float*)d_in[0];
  const float* cosb = (const float*)d_in[1];
  const float* sinb = (const float*)d_in[2];
  // d_in[3]: causal mask, applied analytically
  const float* Wq = (const float*)d_in[4];
  const float* Wk = (const float*)d_in[5];
  const float* Wv = (const float*)d_in[6];
  const float* Wo = (const float*)d_in[7];
  const float* qw = (const float*)d_in[8];
  const float* kw = (const float*)d_in[9];
  float* out = (float*)d_out;

  char* ws = (char*)d_ws;
  short* hsb = (short*)ws;                        // [0, 10.49M)  2048x2560
  short* WT  = (short*)(ws + 10485760);           // [10.49, 41.94M) 6144x2560 fused
  short* WkT = WT + (size_t)4096 * 2560;
  short* WvT = WT + (size_t)5120 * 2560;
  short* Cq  = (short*)(ws + 41943040);           // [41.94, 67.11M) 2048x6144 QKV
  short* ao  = (short*)ws;                        // [0, 16.78M) alias hsb+WT-head (dead)
  short* WoT = (short*)(ws + 20971520);           // [20.97, 41.94M) alias WT-tail (dead)

  dim3 blk(256), cblk(64, 4);
  convT_kernel<<<dim3(40, 64), cblk, 0, stream>>>(Wq, WT, 2560, 4096);
  convT_kernel<<<dim3(40, 16), cblk, 0, stream>>>(Wk, WkT, 2560, 1024);
  convT_kernel<<<dim3(40, 16), cblk, 0, stream>>>(Wv, WvT, 2560, 1024);
  conv16_kernel<<<5120, blk, 0, stream>>>(hs, hsb, 1310720);
  // fused QKV projection: 2048 x 6144 = hsb @ WT^T
  gemm_bb<1><<<dim3(48, 16), blk, 0, stream>>>(hsb, WT, Cq, 6144, 2560);
  normrope_kernel<<<16384, blk, 0, stream>>>(Cq, cosb, sinb, qw, 5, 0);
  normrope_kernel<<<4096,  blk, 0, stream>>>(Cq, cosb, sinb, kw, 3, 4096);
  convT_kernel<<<dim3(64, 40), cblk, 0, stream>>>(Wo, WoT, 4096, 2560);
  attn_kernel<<<dim3(8, 32), dim3(512), 0, stream>>>(Cq, ao);
  gemm_bb<0><<<dim3(20, 16), blk, 0, stream>>>(ao, WoT, out, 2560, 4096);
}